// Round 1
// baseline (72.670 us; speedup 1.0000x reference)
//
#include <hip/hip_runtime.h>

// Problem constants (B, I, C, U, S) = (256, 8, 1152, 10, 16)
#define B_DIM 256
#define I_DIM 8
#define C_DIM 1152
#define U_DIM 10
#define S_DIM 16
#define T_DIM (I_DIM * C_DIM)   // 9216 = flattened (i,c)
#define NCHUNK 8                // batch chunks for partial reduction

// Kernel 1: partial batch-reduce of x [B, I, C] -> partial [NCHUNK][T_DIM]
// Each block handles 256 consecutive t = i*C + c values; blockIdx.y = batch chunk.
// Fully coalesced: per b-iteration the block reads a contiguous 1 KB segment.
__global__ __launch_bounds__(256) void batch_reduce_kernel(
    const float* __restrict__ x, float* __restrict__ partial) {
    const int t = blockIdx.x * 256 + threadIdx.x;      // 0..9215
    const int k = blockIdx.y;                          // 0..7
    const float* p = x + (size_t)(k * (B_DIM / NCHUNK)) * T_DIM + t;
    float acc = 0.f;
#pragma unroll
    for (int b = 0; b < B_DIM / NCHUNK; ++b)
        acc += p[(size_t)b * T_DIM];
    partial[k * T_DIM + t] = acc;
}

// Kernel 2: one thread per (c, s). Holds all U=10 values in registers, so the
// softmax over U is purely thread-local; reductions over S use wave shuffles
// (16-thread groups are aligned within a 64-lane wave).
__global__ __launch_bounds__(256) void routing_kernel(
    const float* __restrict__ partial, const float* __restrict__ W,
    float* __restrict__ out) {
    const int g = blockIdx.x * 256 + threadIdx.x;      // 0..18431
    const int c = g >> 4;
    const int s = g & 15;

    // xs[i] = sum_k partial[k][i*C + c]  (broadcast across the 16 s-threads; L1/L2 hit)
    float xs[I_DIM];
#pragma unroll
    for (int i = 0; i < I_DIM; ++i) {
        float a = 0.f;
#pragma unroll
        for (int k = 0; k < NCHUNK; ++k)
            a += partial[k * T_DIM + i * C_DIM + c];
        xs[i] = a;
    }

    // u_sum[u] for this (c,s): dot(W[c,u,s,:], xs)   W contiguous in i (8 floats)
    float us[U_DIM];
#pragma unroll
    for (int u = 0; u < U_DIM; ++u) {
        const float4* w = (const float4*)(W + (((size_t)c * U_DIM + u) * S_DIM + s) * I_DIM);
        float4 w0 = w[0], w1 = w[1];
        us[u] = w0.x * xs[0] + w0.y * xs[1] + w0.z * xs[2] + w0.w * xs[3] +
                w1.x * xs[4] + w1.y * xs[5] + w1.z * xs[6] + w1.w * xs[7];
    }

    float bij[U_DIM];
#pragma unroll
    for (int u = 0; u < U_DIM; ++u) bij[u] = 0.f;
    float v[U_DIM];

    for (int it = 0; it < 3; ++it) {
        // softmax over U — all in registers
        float m = bij[0];
#pragma unroll
        for (int u = 1; u < U_DIM; ++u) m = fmaxf(m, bij[u]);
        float e[U_DIM];
        float sum = 0.f;
#pragma unroll
        for (int u = 0; u < U_DIM; ++u) { e[u] = expf(bij[u] - m); sum += e[u]; }
        const float inv = 1.f / sum;

#pragma unroll
        for (int u = 0; u < U_DIM; ++u) {
            const float cij = e[u] * inv;
            const float sj = cij * us[u];
            // |s|^2 over S=16 via butterfly shuffle (group stays inside wave)
            float msq = sj * sj;
#pragma unroll
            for (int w = 1; w < 16; w <<= 1) msq += __shfl_xor(msq, w);
            const float mag = sqrtf(msq);
            const float vv = (msq / (1.f + msq)) * (sj / mag);
            v[u] = vv;
            // agreement: dot(u_sum, v)/B over S
            float a = us[u] * vv;
#pragma unroll
            for (int w = 1; w < 16; w <<= 1) a += __shfl_xor(a, w);
            bij[u] += a * (1.f / (float)B_DIM);
        }
    }

#pragma unroll
    for (int u = 0; u < U_DIM; ++u)
        out[(size_t)c * (U_DIM * S_DIM) + u * S_DIM + s] = v[u];
}

extern "C" void kernel_launch(void* const* d_in, const int* in_sizes, int n_in,
                              void* d_out, int out_size, void* d_ws, size_t ws_size,
                              hipStream_t stream) {
    const float* x = (const float*)d_in[0];   // [256, 8, 1152]
    const float* W = (const float*)d_in[1];   // [1, 1152, 10, 16, 8]
    float* out = (float*)d_out;               // [1152, 10, 16]
    float* partial = (float*)d_ws;            // [8][9216] = 294,912 bytes

    dim3 g1(T_DIM / 256, NCHUNK);             // 36 x 8 blocks
    batch_reduce_kernel<<<g1, 256, 0, stream>>>(x, partial);

    const int threads2 = C_DIM * S_DIM;       // 18432
    routing_kernel<<<threads2 / 256, 256, 0, stream>>>(partial, W, out);
}

// Round 2
// 72.298 us; speedup vs baseline: 1.0051x; 1.0051x over previous
//
#include <hip/hip_runtime.h>

// Problem constants (B, I, C, U, S) = (256, 8, 1152, 10, 16)
#define B_DIM 256
#define I_DIM 8
#define C_DIM 1152
#define U_DIM 10
#define S_DIM 16
#define T_DIM (I_DIM * C_DIM)   // 9216 = flattened (i,c)
#define NCHUNK 8                // batch chunks for partial reduction

// Kernel 1: partial batch-reduce of x [B, I, C] -> partial [NCHUNK][T_DIM]
// Each block handles 256 consecutive t = i*C + c values; blockIdx.y = batch chunk.
// Fully coalesced: per b-iteration the block reads a contiguous 1 KB segment.
__global__ __launch_bounds__(256) void batch_reduce_kernel(
    const float* __restrict__ x, float* __restrict__ partial) {
    const int t = blockIdx.x * 256 + threadIdx.x;      // 0..9215
    const int k = blockIdx.y;                          // 0..7
    const float* p = x + (size_t)(k * (B_DIM / NCHUNK)) * T_DIM + t;
    float acc = 0.f;
#pragma unroll
    for (int b = 0; b < B_DIM / NCHUNK; ++b)
        acc += p[(size_t)b * T_DIM];
    partial[k * T_DIM + t] = acc;
}

// Kernel 2: 64-thread blocks, 4 capsules (c) per block -> 288 blocks spread
// across all 256 CUs (vs 72 blocks before). Chunk-partials are folded
// cooperatively through LDS (4 global loads/thread instead of 64 broadcast
// loads/thread). Routing is register-resident; S=16 reductions via in-wave
// butterfly shuffles.
__global__ __launch_bounds__(64) void routing_kernel(
    const float* __restrict__ partial, const float* __restrict__ W,
    float* __restrict__ out) {
    __shared__ float foldbuf[2][32];
    __shared__ float xs_lds[32];                       // [c_local][i]

    const int tid = threadIdx.x;
    const int c0 = blockIdx.x * 4;

    // cooperative fold: partial[8][i*C + c] -> xs[c_local][i]
    {
        const int p = tid & 31;                        // p = c_local*8 + i
        const int grp = tid >> 5;                      // k-range [grp*4, grp*4+4)
        const int c_l = p >> 3, ii = p & 7;
        const float* pp = partial + (size_t)grp * 4 * T_DIM + ii * C_DIM + (c0 + c_l);
        float a = 0.f;
#pragma unroll
        for (int k = 0; k < 4; ++k) a += pp[(size_t)k * T_DIM];
        foldbuf[grp][p] = a;
    }
    __syncthreads();
    if (tid < 32) xs_lds[tid] = foldbuf[0][tid] + foldbuf[1][tid];
    __syncthreads();

    const int c_local = tid >> 4;                      // 0..3
    const int s = tid & 15;
    const int c = c0 + c_local;

    float xs[I_DIM];
#pragma unroll
    for (int i = 0; i < I_DIM; ++i) xs[i] = xs_lds[c_local * 8 + i];

    // u_sum[u] for this (c,s): dot(W[c,u,s,:], xs)   W contiguous in i (8 floats)
    float us[U_DIM];
#pragma unroll
    for (int u = 0; u < U_DIM; ++u) {
        const float4* w = (const float4*)(W + (((size_t)c * U_DIM + u) * S_DIM + s) * I_DIM);
        float4 w0 = w[0], w1 = w[1];
        us[u] = w0.x * xs[0] + w0.y * xs[1] + w0.z * xs[2] + w0.w * xs[3] +
                w1.x * xs[4] + w1.y * xs[5] + w1.z * xs[6] + w1.w * xs[7];
    }

    float bij[U_DIM];
    float v[U_DIM];

    // --- iteration 0: softmax(0) == 1/10 exactly; compute v and agreement ---
#pragma unroll
    for (int u = 0; u < U_DIM; ++u) {
        const float sj = 0.1f * us[u];
        float msq = sj * sj;
#pragma unroll
        for (int w = 1; w < 16; w <<= 1) msq += __shfl_xor(msq, w);
        const float vv = (msq / (1.f + msq)) * (sj * __frsqrt_rn(msq) * rsqrtf(msq) * msq) ; // placeholder removed below
        (void)vv;
        const float mag = sqrtf(msq);
        const float v0 = (msq / (1.f + msq)) * (sj / mag);
        v[u] = v0;
        float a = us[u] * v0;
#pragma unroll
        for (int w = 1; w < 16; w <<= 1) a += __shfl_xor(a, w);
        bij[u] = a * (1.f / (float)B_DIM);
    }

    // --- iterations 1..2: full softmax; last iter skips agreement update ---
#pragma unroll
    for (int it = 1; it < 3; ++it) {
        float m = bij[0];
#pragma unroll
        for (int u = 1; u < U_DIM; ++u) m = fmaxf(m, bij[u]);
        float e[U_DIM];
        float sum = 0.f;
#pragma unroll
        for (int u = 0; u < U_DIM; ++u) { e[u] = __expf(bij[u] - m); sum += e[u]; }
        const float inv = 1.f / sum;

#pragma unroll
        for (int u = 0; u < U_DIM; ++u) {
            const float sj = e[u] * inv * us[u];
            float msq = sj * sj;
#pragma unroll
            for (int w = 1; w < 16; w <<= 1) msq += __shfl_xor(msq, w);
            const float mag = sqrtf(msq);
            const float vv = (msq / (1.f + msq)) * (sj / mag);
            v[u] = vv;
            if (it < 2) {
                float a = us[u] * vv;
#pragma unroll
                for (int w = 1; w < 16; w <<= 1) a += __shfl_xor(a, w);
                bij[u] += a * (1.f / (float)B_DIM);
            }
        }
    }

#pragma unroll
    for (int u = 0; u < U_DIM; ++u)
        out[(size_t)c * (U_DIM * S_DIM) + u * S_DIM + s] = v[u];
}

extern "C" void kernel_launch(void* const* d_in, const int* in_sizes, int n_in,
                              void* d_out, int out_size, void* d_ws, size_t ws_size,
                              hipStream_t stream) {
    const float* x = (const float*)d_in[0];   // [256, 8, 1152]
    const float* W = (const float*)d_in[1];   // [1, 1152, 10, 16, 8]
    float* out = (float*)d_out;               // [1152, 10, 16]
    float* partial = (float*)d_ws;            // [8][9216] = 294,912 bytes

    dim3 g1(T_DIM / 256, NCHUNK);             // 36 x 8 blocks
    batch_reduce_kernel<<<g1, 256, 0, stream>>>(x, partial);

    routing_kernel<<<C_DIM / 4, 64, 0, stream>>>(partial, W, out);
}